// Round 1
// baseline (246.574 us; speedup 1.0000x reference)
//
#include <hip/hip_runtime.h>
#include <hip/hip_bf16.h>

#define N_NODES 10000
#define N_EDGES 320000
#define K_TERMS 5
#define C_IN 128
#define C_OUT 128
#define KDIM (K_TERMS * C_IN)   // 640

// ---------------------------------------------------------------------------
// Kernel 1: CSR offsets via binary search over sorted src array.
// offsets[n] = lower_bound(src, n). offsets[N_NODES] = N_EDGES falls out
// naturally since all src < N_NODES.
// ---------------------------------------------------------------------------
__global__ void build_offsets(const int* __restrict__ src, int* __restrict__ offsets) {
    int n = blockIdx.x * blockDim.x + threadIdx.x;
    if (n > N_NODES) return;
    int lo = 0, hi = N_EDGES;
    while (lo < hi) {
        int mid = (lo + hi) >> 1;
        if (src[mid] < n) lo = mid + 1; else hi = mid;
    }
    offsets[n] = lo;
}

// ---------------------------------------------------------------------------
// Kernel 2: per-node segment reduction.
// One 128-thread team per node (2 teams per 256-thread block).
// Thread = channel i; accumulates res[k][i] for k=0..4 in registers, then
// writes R[n][k*128+i] (f32) to workspace. Nodes with zero edges write zeros.
// ---------------------------------------------------------------------------
__global__ __launch_bounds__(256) void scatter_segments(
        const float* __restrict__ h,
        const float* __restrict__ X,
        const int* __restrict__ dst,
        const int* __restrict__ offsets,
        float* __restrict__ R) {
    int team = threadIdx.x >> 7;          // 0 or 1
    int lane = threadIdx.x & 127;         // channel
    int node = blockIdx.x * 2 + team;
    if (node >= N_NODES) return;

    float r0 = 0.f, r1 = 0.f, r2 = 0.f, r3 = 0.f, r4 = 0.f;
    int e0 = offsets[node];
    int e1 = offsets[node + 1];

    for (int e = e0; e < e1; ++e) {
        int d = dst[e];
        float hv = h[d * C_IN + lane];
        float x0 = X[e * K_TERMS + 0];
        float x1 = X[e * K_TERMS + 1];
        float x2 = X[e * K_TERMS + 2];
        float x3 = X[e * K_TERMS + 3];
        float x4 = X[e * K_TERMS + 4];
        r0 = fmaf(x0, hv, r0);
        r1 = fmaf(x1, hv, r1);
        r2 = fmaf(x2, hv, r2);
        r3 = fmaf(x3, hv, r3);
        r4 = fmaf(x4, hv, r4);
    }

    float* Rn = R + (size_t)node * KDIM;
    Rn[0 * C_IN + lane] = r0;
    Rn[1 * C_IN + lane] = r1;
    Rn[2 * C_IN + lane] = r2;
    Rn[3 * C_IN + lane] = r3;
    Rn[4 * C_IN + lane] = r4;
}

// ---------------------------------------------------------------------------
// Kernel 3: out(10000x128) = R(10000x640) * Wf(640x128) + bias.
// fp32 vector GEMM, tile M=64 x N=128, KC=32, 256 threads, 4x8 per thread.
// Thread (ty,tx) 16x16; m = ty+16*i, o = tx+16*j -> conflict-free LDS reads
// (16 consecutive addresses, 4-lane same-address broadcast).
// ---------------------------------------------------------------------------
#define TM 64
#define KC 32
__global__ __launch_bounds__(256) void gemm_out(
        const float* __restrict__ R,
        const float* __restrict__ W,      // (640,128) row-major
        const float* __restrict__ bias,
        float* __restrict__ out) {
    __shared__ float As[KC][TM + 1];      // [k][m], padded
    __shared__ float Bs[KC][C_OUT];       // [k][o]

    int m0 = blockIdx.x * TM;
    int tid = threadIdx.x;
    int ty = tid >> 4;                    // 0..15
    int tx = tid & 15;                    // 0..15

    float acc[4][8];
#pragma unroll
    for (int i = 0; i < 4; ++i)
#pragma unroll
        for (int j = 0; j < 8; ++j) acc[i][j] = 0.f;

    for (int kc = 0; kc < KDIM; kc += KC) {
        // Load A tile: 64x32 = 2048 elems, 8 per thread, coalesced in k.
#pragma unroll
        for (int r = 0; r < 8; ++r) {
            int idx = r * 256 + tid;
            int m = idx >> 5;             // 0..63
            int k = idx & 31;
            int n = m0 + m;
            As[k][m] = (n < N_NODES) ? R[(size_t)n * KDIM + kc + k] : 0.f;
        }
        // Load B tile: 32x128 = 4096 elems, 16 per thread, coalesced in o.
#pragma unroll
        for (int r = 0; r < 16; ++r) {
            int idx = r * 256 + tid;
            int k = idx >> 7;             // 0..31
            int o = idx & 127;
            Bs[k][o] = W[(size_t)(kc + k) * C_OUT + o];
        }
        __syncthreads();

#pragma unroll
        for (int k = 0; k < KC; ++k) {
            float a[4], b[8];
#pragma unroll
            for (int i = 0; i < 4; ++i) a[i] = As[k][ty + 16 * i];
#pragma unroll
            for (int j = 0; j < 8; ++j) b[j] = Bs[k][tx + 16 * j];
#pragma unroll
            for (int i = 0; i < 4; ++i)
#pragma unroll
                for (int j = 0; j < 8; ++j)
                    acc[i][j] = fmaf(a[i], b[j], acc[i][j]);
        }
        __syncthreads();
    }

#pragma unroll
    for (int i = 0; i < 4; ++i) {
        int n = m0 + ty + 16 * i;
        if (n >= N_NODES) continue;
#pragma unroll
        for (int j = 0; j < 8; ++j) {
            int o = tx + 16 * j;
            out[(size_t)n * C_OUT + o] = acc[i][j] + bias[o];
        }
    }
}

// ---------------------------------------------------------------------------
extern "C" void kernel_launch(void* const* d_in, const int* in_sizes, int n_in,
                              void* d_out, int out_size, void* d_ws, size_t ws_size,
                              hipStream_t stream) {
    const float* h      = (const float*)d_in[0];   // (10000,128)
    const float* X      = (const float*)d_in[1];   // (320000,5)
    const int*   ei     = (const int*)d_in[2];     // (2,320000) int32
    // d_in[3] = batch_node (unused)
    const float* weight = (const float*)d_in[4];   // (5,128,128) == Wf(640,128)
    const float* bias   = (const float*)d_in[5];   // (128,)
    float* out = (float*)d_out;

    const int* src = ei;
    const int* dst = ei + N_EDGES;

    // Workspace layout: offsets[10001] ints at start; R (10000x640 f32) at +64KB.
    int*   offsets = (int*)d_ws;
    float* R       = (float*)((char*)d_ws + (64 << 10));

    {
        int threads = 256;
        int blocks = (N_NODES + 1 + threads - 1) / threads;
        build_offsets<<<blocks, threads, 0, stream>>>(src, offsets);
    }
    {
        int blocks = (N_NODES + 1) / 2;   // 5000, 2 nodes per block
        scatter_segments<<<blocks, 256, 0, stream>>>(h, X, dst, offsets, R);
    }
    {
        int blocks = (N_NODES + TM - 1) / TM;  // 157
        gemm_out<<<blocks, 256, 0, stream>>>(R, weight, bias, out);
    }
}

// Round 2
// 142.199 us; speedup vs baseline: 1.7340x; 1.7340x over previous
//
#include <hip/hip_runtime.h>
#include <hip/hip_bf16.h>

#define N_NODES 10000
#define N_EDGES 320000
#define K_TERMS 5
#define C_IN 128
#define C_OUT 128
#define KDIM (K_TERMS * C_IN)   // 640

// ---------------------------------------------------------------------------
// Kernel 1: CSR offsets via binary search over sorted src array.
// ---------------------------------------------------------------------------
__global__ void build_offsets(const int* __restrict__ src, int* __restrict__ offsets) {
    int n = blockIdx.x * blockDim.x + threadIdx.x;
    if (n > N_NODES) return;
    int lo = 0, hi = N_EDGES;
    while (lo < hi) {
        int mid = (lo + hi) >> 1;
        if (src[mid] < n) lo = mid + 1; else hi = mid;
    }
    offsets[n] = lo;
}

// ---------------------------------------------------------------------------
// Kernel 2: per-node segment reduction. ONE WAVE (64 lanes) per node.
// Lane l holds channels {2l, 2l+1} as float2.
// dst indices for up to 64 edges are fetched lane-parallel (1 load instr),
// then broadcast via __shfl -> no serial dst->h dependent chain.
// j-loop unrolled x2 so two independent h-row gathers are in flight.
// ---------------------------------------------------------------------------
__global__ __launch_bounds__(256) void scatter_segments(
        const float* __restrict__ h,
        const float* __restrict__ X,
        const int* __restrict__ dst,
        const int* __restrict__ offsets,
        float* __restrict__ R) {
    const int wave = threadIdx.x >> 6;        // 0..3
    const int lane = threadIdx.x & 63;
    const int node = blockIdx.x * 4 + wave;   // grid = 2500 -> exact
    if (node >= N_NODES) return;

    const float2* __restrict__ h2 = (const float2*)h;   // row = 64 float2

    float2 a0 = {0.f, 0.f}, a1 = {0.f, 0.f}, a2 = {0.f, 0.f},
           a3 = {0.f, 0.f}, a4 = {0.f, 0.f};

    const int e0 = offsets[node];
    const int e1 = offsets[node + 1];

    for (int base = e0; base < e1; base += 64) {
        const int ei = base + lane;
        // lane-parallel fetch of up to 64 dst indices (clamped; e1>e0 here)
        const int dv = dst[(ei < e1) ? ei : (e1 - 1)];
        const int cnt = min(64, e1 - base);

        int j = 0;
        for (; j + 1 < cnt; j += 2) {
            const int d0 = __shfl(dv, j);
            const int d1 = __shfl(dv, j + 1);
            const int ea = base + j;
            const int eb = base + j + 1;
            // X broadcasts (same addr all lanes) - independent, prefetchable
            const float xa0 = X[ea * 5 + 0], xa1 = X[ea * 5 + 1],
                        xa2 = X[ea * 5 + 2], xa3 = X[ea * 5 + 3],
                        xa4 = X[ea * 5 + 4];
            const float xb0 = X[eb * 5 + 0], xb1 = X[eb * 5 + 1],
                        xb2 = X[eb * 5 + 2], xb3 = X[eb * 5 + 3],
                        xb4 = X[eb * 5 + 4];
            const float2 ha = h2[(size_t)d0 * 64 + lane];
            const float2 hb = h2[(size_t)d1 * 64 + lane];
            a0.x = fmaf(xa0, ha.x, a0.x); a0.y = fmaf(xa0, ha.y, a0.y);
            a1.x = fmaf(xa1, ha.x, a1.x); a1.y = fmaf(xa1, ha.y, a1.y);
            a2.x = fmaf(xa2, ha.x, a2.x); a2.y = fmaf(xa2, ha.y, a2.y);
            a3.x = fmaf(xa3, ha.x, a3.x); a3.y = fmaf(xa3, ha.y, a3.y);
            a4.x = fmaf(xa4, ha.x, a4.x); a4.y = fmaf(xa4, ha.y, a4.y);
            a0.x = fmaf(xb0, hb.x, a0.x); a0.y = fmaf(xb0, hb.y, a0.y);
            a1.x = fmaf(xb1, hb.x, a1.x); a1.y = fmaf(xb1, hb.y, a1.y);
            a2.x = fmaf(xb2, hb.x, a2.x); a2.y = fmaf(xb2, hb.y, a2.y);
            a3.x = fmaf(xb3, hb.x, a3.x); a3.y = fmaf(xb3, hb.y, a3.y);
            a4.x = fmaf(xb4, hb.x, a4.x); a4.y = fmaf(xb4, hb.y, a4.y);
        }
        if (j < cnt) {
            const int d0 = __shfl(dv, j);
            const int ea = base + j;
            const float x0 = X[ea * 5 + 0], x1 = X[ea * 5 + 1],
                        x2 = X[ea * 5 + 2], x3 = X[ea * 5 + 3],
                        x4 = X[ea * 5 + 4];
            const float2 ha = h2[(size_t)d0 * 64 + lane];
            a0.x = fmaf(x0, ha.x, a0.x); a0.y = fmaf(x0, ha.y, a0.y);
            a1.x = fmaf(x1, ha.x, a1.x); a1.y = fmaf(x1, ha.y, a1.y);
            a2.x = fmaf(x2, ha.x, a2.x); a2.y = fmaf(x2, ha.y, a2.y);
            a3.x = fmaf(x3, ha.x, a3.x); a3.y = fmaf(x3, ha.y, a3.y);
            a4.x = fmaf(x4, ha.x, a4.x); a4.y = fmaf(x4, ha.y, a4.y);
        }
    }

    float2* __restrict__ Rn = (float2*)(R + (size_t)node * KDIM);
    Rn[0 * 64 + lane] = a0;
    Rn[1 * 64 + lane] = a1;
    Rn[2 * 64 + lane] = a2;
    Rn[3 * 64 + lane] = a3;
    Rn[4 * 64 + lane] = a4;
}

// ---------------------------------------------------------------------------
// Kernel 3: out(10000x128) = R(10000x640) * W(640x128) + bias.
// TM=16 -> 625 blocks (vs 157) for occupancy. 256 threads; thread (ty,tx)
// with ty=tid>>5 (rows 2ty,2ty+1), tx=tid&31 (cols 4tx..4tx+3 as float4).
// As[m][k]: conflict-free writes (consecutive k), broadcast reads.
// Bs read via ds_read_b128.
// ---------------------------------------------------------------------------
#define TM 16
#define KC 32
__global__ __launch_bounds__(256) void gemm_out(
        const float* __restrict__ R,
        const float* __restrict__ W,      // (640,128) row-major
        const float* __restrict__ bias,
        float* __restrict__ out) {
    __shared__ float As[TM][KC];          // 2 KB
    __shared__ float Bs[KC][C_OUT];       // 16 KB

    const int m0 = blockIdx.x * TM;       // 625 * 16 = 10000 exact
    const int tid = threadIdx.x;
    const int ty = tid >> 5;              // 0..7
    const int tx = tid & 31;              // 0..31

    float4 acc0 = {0.f, 0.f, 0.f, 0.f};
    float4 acc1 = {0.f, 0.f, 0.f, 0.f};

    for (int kc = 0; kc < KDIM; kc += KC) {
        // A tile: 16x32 = 512 elems, 2 per thread, coalesced over k.
#pragma unroll
        for (int r = 0; r < 2; ++r) {
            const int idx = r * 256 + tid;
            const int m = idx >> 5;
            const int k = idx & 31;
            As[m][k] = R[(size_t)(m0 + m) * KDIM + kc + k];
        }
        // B tile: 32x128 = 1024 float4, 4 per thread, coalesced.
#pragma unroll
        for (int r = 0; r < 4; ++r) {
            const int idx = r * 256 + tid;
            const int k = idx >> 5;
            const int o4 = idx & 31;
            ((float4*)&Bs[k][0])[o4] = ((const float4*)(W + (size_t)(kc + k) * C_OUT))[o4];
        }
        __syncthreads();

#pragma unroll
        for (int k = 0; k < KC; ++k) {
            const float va0 = As[2 * ty][k];
            const float va1 = As[2 * ty + 1][k];
            const float4 b = ((const float4*)&Bs[k][0])[tx];
            acc0.x = fmaf(va0, b.x, acc0.x);
            acc0.y = fmaf(va0, b.y, acc0.y);
            acc0.z = fmaf(va0, b.z, acc0.z);
            acc0.w = fmaf(va0, b.w, acc0.w);
            acc1.x = fmaf(va1, b.x, acc1.x);
            acc1.y = fmaf(va1, b.y, acc1.y);
            acc1.z = fmaf(va1, b.z, acc1.z);
            acc1.w = fmaf(va1, b.w, acc1.w);
        }
        __syncthreads();
    }

    const float4 bv = ((const float4*)bias)[tx];
    acc0.x += bv.x; acc0.y += bv.y; acc0.z += bv.z; acc0.w += bv.w;
    acc1.x += bv.x; acc1.y += bv.y; acc1.z += bv.z; acc1.w += bv.w;

    float4* o0 = (float4*)(out + (size_t)(m0 + 2 * ty) * C_OUT);
    float4* o1 = (float4*)(out + (size_t)(m0 + 2 * ty + 1) * C_OUT);
    o0[tx] = acc0;
    o1[tx] = acc1;
}

// ---------------------------------------------------------------------------
extern "C" void kernel_launch(void* const* d_in, const int* in_sizes, int n_in,
                              void* d_out, int out_size, void* d_ws, size_t ws_size,
                              hipStream_t stream) {
    const float* h      = (const float*)d_in[0];   // (10000,128)
    const float* X      = (const float*)d_in[1];   // (320000,5)
    const int*   ei     = (const int*)d_in[2];     // (2,320000) int32
    const float* weight = (const float*)d_in[4];   // (5,128,128) == W(640,128)
    const float* bias   = (const float*)d_in[5];   // (128,)
    float* out = (float*)d_out;

    const int* src = ei;
    const int* dst = ei + N_EDGES;

    int*   offsets = (int*)d_ws;
    float* R       = (float*)((char*)d_ws + (64 << 10));

    {
        int threads = 256;
        int blocks = (N_NODES + 1 + threads - 1) / threads;
        build_offsets<<<blocks, threads, 0, stream>>>(src, offsets);
    }
    {
        int blocks = (N_NODES + 3) / 4;   // 2500, 1 wave per node
        scatter_segments<<<blocks, 256, 0, stream>>>(h, X, dst, offsets, R);
    }
    {
        int blocks = N_NODES / TM;        // 625
        gemm_out<<<blocks, 256, 0, stream>>>(R, weight, bias, out);
    }
}

// Round 3
// 135.623 us; speedup vs baseline: 1.8181x; 1.0485x over previous
//
#include <hip/hip_runtime.h>

#define N_NODES 10000
#define N_EDGES 320000
#define C_IN 128
#define C_OUT 128
#define KDIM 640            // K_TERMS * C_IN

typedef __attribute__((ext_vector_type(8))) short short8;   // 8 bf16 (4 VGPRs)
typedef __attribute__((ext_vector_type(4))) float floatx4;  // MFMA C/D

// ---- bf16 helpers (bit tricks, no lib dependency) -------------------------
__device__ __forceinline__ unsigned short f2bf(float f) {
    unsigned int b = __float_as_uint(f);
    b = (b + 0x7FFFu + ((b >> 16) & 1u)) >> 16;   // round-to-nearest-even
    return (unsigned short)b;
}
__device__ __forceinline__ unsigned int pack2(float x, float y) {
    return (unsigned int)f2bf(x) | ((unsigned int)f2bf(y) << 16);
}
__device__ __forceinline__ float2 unpack2(unsigned int u) {
    float2 r;
    r.x = __uint_as_float(u << 16);
    r.y = __uint_as_float(u & 0xFFFF0000u);
    return r;
}

// ---------------------------------------------------------------------------
// Kernel 1: CSR offsets via binary search over sorted src.
// ---------------------------------------------------------------------------
__global__ void build_offsets(const int* __restrict__ src, int* __restrict__ offsets) {
    int n = blockIdx.x * blockDim.x + threadIdx.x;
    if (n > N_NODES) return;
    int lo = 0, hi = N_EDGES;
    while (lo < hi) {
        int mid = (lo + hi) >> 1;
        if (src[mid] < n) lo = mid + 1; else hi = mid;
    }
    offsets[n] = lo;
}

// ---------------------------------------------------------------------------
// Kernel 1b: h (f32) -> hb (bf16). float4 -> uint2, coalesced.
// ---------------------------------------------------------------------------
__global__ __launch_bounds__(256) void conv_h(const float* __restrict__ h,
                                              unsigned int* __restrict__ hb2) {
    int t = blockIdx.x * blockDim.x + threadIdx.x;   // 320000 threads
    if (t >= N_NODES * C_IN / 4) return;
    float4 v = ((const float4*)h)[t];
    uint2 o;
    o.x = pack2(v.x, v.y);
    o.y = pack2(v.z, v.w);
    ((uint2*)hb2)[t] = o;
}

// ---------------------------------------------------------------------------
// Kernel 1c: W (640x128 f32) -> Wt (128x640 bf16), LDS-tiled transpose.
// grid (20,4), block (32,8).
// ---------------------------------------------------------------------------
__global__ __launch_bounds__(256) void conv_w(const float* __restrict__ W,
                                              unsigned short* __restrict__ Wt) {
    __shared__ float tile[32][33];
    const int tx = threadIdx.x, ty = threadIdx.y;
    const int k0 = blockIdx.x * 32, o0 = blockIdx.y * 32;
#pragma unroll
    for (int i = 0; i < 4; ++i)
        tile[ty + 8 * i][tx] = W[(size_t)(k0 + ty + 8 * i) * C_OUT + o0 + tx];
    __syncthreads();
#pragma unroll
    for (int i = 0; i < 4; ++i)
        Wt[(size_t)(o0 + ty + 8 * i) * KDIM + k0 + tx] = f2bf(tile[tx][ty + 8 * i]);
}

// ---------------------------------------------------------------------------
// Kernel 2: segment scatter. One wave per node; lane = channel pair (2l,2l+1).
// Per 64-edge window: dst + X fetched lane-parallel (1 + 5 vmem), values
// distributed via __shfl (v_readlane, VALU). Inner loop unrolled x4 -> 4
// independent bf16 h-row gathers in flight.
// ---------------------------------------------------------------------------
__device__ __forceinline__ void acc_edge(unsigned int u,
        float x0, float x1, float x2, float x3, float x4,
        float2& a0, float2& a1, float2& a2, float2& a3, float2& a4) {
    float2 hv = unpack2(u);
    a0.x = fmaf(x0, hv.x, a0.x); a0.y = fmaf(x0, hv.y, a0.y);
    a1.x = fmaf(x1, hv.x, a1.x); a1.y = fmaf(x1, hv.y, a1.y);
    a2.x = fmaf(x2, hv.x, a2.x); a2.y = fmaf(x2, hv.y, a2.y);
    a3.x = fmaf(x3, hv.x, a3.x); a3.y = fmaf(x3, hv.y, a3.y);
    a4.x = fmaf(x4, hv.x, a4.x); a4.y = fmaf(x4, hv.y, a4.y);
}

__global__ __launch_bounds__(256) void scatter_segments(
        const unsigned int* __restrict__ h2,   // bf16x2, 64 per node row
        const float* __restrict__ X,
        const int* __restrict__ dst,
        const int* __restrict__ offsets,
        unsigned int* __restrict__ Rb2) {      // bf16x2, 320 per node row
    const int wave = threadIdx.x >> 6;
    const int lane = threadIdx.x & 63;
    const int node = blockIdx.x * 4 + wave;    // grid 2500 -> exact
    if (node >= N_NODES) return;

    float2 a0 = {0.f, 0.f}, a1 = {0.f, 0.f}, a2 = {0.f, 0.f},
           a3 = {0.f, 0.f}, a4 = {0.f, 0.f};

    const int e0 = offsets[node];
    const int e1 = offsets[node + 1];

    for (int base = e0; base < e1; base += 64) {
        const int cnt = min(64, e1 - base);
        const int ed = base + ((lane < cnt) ? lane : (cnt - 1));
        const int dv = dst[ed];
        const float* Xp = X + (size_t)ed * 5;
        const float xk0 = Xp[0], xk1 = Xp[1], xk2 = Xp[2], xk3 = Xp[3], xk4 = Xp[4];

        int j = 0;
        for (; j + 3 < cnt; j += 4) {
            const int d0 = __shfl(dv, j + 0);
            const int d1 = __shfl(dv, j + 1);
            const int d2 = __shfl(dv, j + 2);
            const int d3 = __shfl(dv, j + 3);
            const unsigned int u0 = h2[(size_t)d0 * 64 + lane];
            const unsigned int u1 = h2[(size_t)d1 * 64 + lane];
            const unsigned int u2 = h2[(size_t)d2 * 64 + lane];
            const unsigned int u3 = h2[(size_t)d3 * 64 + lane];
            acc_edge(u0, __shfl(xk0, j + 0), __shfl(xk1, j + 0), __shfl(xk2, j + 0),
                         __shfl(xk3, j + 0), __shfl(xk4, j + 0), a0, a1, a2, a3, a4);
            acc_edge(u1, __shfl(xk0, j + 1), __shfl(xk1, j + 1), __shfl(xk2, j + 1),
                         __shfl(xk3, j + 1), __shfl(xk4, j + 1), a0, a1, a2, a3, a4);
            acc_edge(u2, __shfl(xk0, j + 2), __shfl(xk1, j + 2), __shfl(xk2, j + 2),
                         __shfl(xk3, j + 2), __shfl(xk4, j + 2), a0, a1, a2, a3, a4);
            acc_edge(u3, __shfl(xk0, j + 3), __shfl(xk1, j + 3), __shfl(xk2, j + 3),
                         __shfl(xk3, j + 3), __shfl(xk4, j + 3), a0, a1, a2, a3, a4);
        }
        for (; j < cnt; ++j) {
            const int d0 = __shfl(dv, j);
            const unsigned int u0 = h2[(size_t)d0 * 64 + lane];
            acc_edge(u0, __shfl(xk0, j), __shfl(xk1, j), __shfl(xk2, j),
                         __shfl(xk3, j), __shfl(xk4, j), a0, a1, a2, a3, a4);
        }
    }

    unsigned int* Rn = Rb2 + (size_t)node * 320;   // node row = 320 uints
    Rn[0 * 64 + lane] = pack2(a0.x, a0.y);
    Rn[1 * 64 + lane] = pack2(a1.x, a1.y);
    Rn[2 * 64 + lane] = pack2(a2.x, a2.y);
    Rn[3 * 64 + lane] = pack2(a3.x, a3.y);
    Rn[4 * 64 + lane] = pack2(a4.x, a4.y);
}

// ---------------------------------------------------------------------------
// Kernel 3: out(10000x128) = Rb(10000x640 bf16) x Wt(128x640 bf16)^T + bias.
// MFMA 16x16x32 bf16, gemm_bt structure (both operands row-major in k).
// Block: 256 thr = 4 waves; tile M=64 (16 rows/wave) x N=128, KC=64.
// Fragments: a: lane reads own-row (lane&15), k = quad*8..+7 (ds_read_b128).
// D: row = quad*4+reg, col = lane&15 (m89/m91-verified layout).
// LDS rows padded to 72 bf16 (144 B) -> b128 reads are 2-way max (free).
// ---------------------------------------------------------------------------
__global__ __launch_bounds__(256) void gemm_mfma(
        const unsigned short* __restrict__ Rb,
        const unsigned short* __restrict__ Wt,
        const float* __restrict__ bias,
        float* __restrict__ out) {
    __shared__ unsigned short As[64][72];    // 9.2 KB
    __shared__ unsigned short Bs[128][72];   // 18.4 KB

    const int tid = threadIdx.x;
    const int wave = tid >> 6, lane = tid & 63;
    const int col = lane & 15, quad = lane >> 4;
    const int m0 = blockIdx.x * 64;

    floatx4 acc[8];
#pragma unroll
    for (int t = 0; t < 8; ++t) acc[t] = (floatx4){0.f, 0.f, 0.f, 0.f};

    for (int kc = 0; kc < KDIM; kc += 64) {
        // Stage A: 64 rows x 64 bf16 = 512 x 16B chunks, 2 per thread.
#pragma unroll
        for (int r = 0; r < 2; ++r) {
            const int c = r * 256 + tid;
            const int row = c >> 3, c8 = c & 7;
            *(int4*)&As[row][c8 * 8] =
                *(const int4*)(Rb + (size_t)(m0 + row) * KDIM + kc + c8 * 8);
        }
        // Stage B: 128 rows x 64 bf16 = 1024 chunks, 4 per thread.
#pragma unroll
        for (int r = 0; r < 4; ++r) {
            const int c = r * 256 + tid;
            const int row = c >> 3, c8 = c & 7;
            *(int4*)&Bs[row][c8 * 8] =
                *(const int4*)(Wt + (size_t)row * KDIM + kc + c8 * 8);
        }
        __syncthreads();

#pragma unroll
        for (int hh = 0; hh < 2; ++hh) {
            const int k0 = hh * 32;
            const short8 af = *(const short8*)&As[wave * 16 + col][k0 + quad * 8];
#pragma unroll
            for (int t = 0; t < 8; ++t) {
                const short8 bf = *(const short8*)&Bs[t * 16 + col][k0 + quad * 8];
                acc[t] = __builtin_amdgcn_mfma_f32_16x16x32_bf16(af, bf, acc[t], 0, 0, 0);
            }
        }
        __syncthreads();
    }

#pragma unroll
    for (int t = 0; t < 8; ++t) {
        const float bv = bias[t * 16 + col];
#pragma unroll
        for (int r = 0; r < 4; ++r) {
            const int m = m0 + wave * 16 + quad * 4 + r;
            if (m < N_NODES)
                out[(size_t)m * C_OUT + t * 16 + col] = acc[t][r] + bv;
        }
    }
}

// ---------------------------------------------------------------------------
extern "C" void kernel_launch(void* const* d_in, const int* in_sizes, int n_in,
                              void* d_out, int out_size, void* d_ws, size_t ws_size,
                              hipStream_t stream) {
    const float* h      = (const float*)d_in[0];   // (10000,128)
    const float* X      = (const float*)d_in[1];   // (320000,5)
    const int*   ei     = (const int*)d_in[2];     // (2,320000)
    const float* weight = (const float*)d_in[4];   // (5,128,128) == W(640,128)
    const float* bias   = (const float*)d_in[5];   // (128,)
    float* out = (float*)d_out;

    const int* src = ei;
    const int* dst = ei + N_EDGES;

    // Workspace layout (ws >= 256 MB):
    //   [0, 64KB)        offsets (10001 ints)
    //   [64KB, +4MB)     hb  : h bf16   (2.56 MB)
    //   [64KB+4MB, ...)  Wtb : Wt bf16  (160 KB)
    //   [64KB+8MB, ...)  Rb  : R bf16   (12.8 MB; gemm may over-read ~60KB, in-bounds)
    char* wsb = (char*)d_ws;
    int*            offsets = (int*)wsb;
    unsigned int*   hb2     = (unsigned int*)(wsb + (64 << 10));
    unsigned short* Wtb     = (unsigned short*)(wsb + (64 << 10) + (4 << 20));
    unsigned short* Rb      = (unsigned short*)(wsb + (64 << 10) + (8 << 20));

    build_offsets<<<(N_NODES + 256) / 256, 256, 0, stream>>>(src, offsets);
    conv_h<<<(N_NODES * C_IN / 4 + 255) / 256, 256, 0, stream>>>(h, hb2);
    conv_w<<<dim3(KDIM / 32, C_OUT / 32), dim3(32, 8), 0, stream>>>(weight, Wtb);
    scatter_segments<<<N_NODES / 4, 256, 0, stream>>>(hb2, X, dst, offsets,
                                                      (unsigned int*)Rb);
    gemm_mfma<<<(N_NODES + 63) / 64, 256, 0, stream>>>(Rb, Wtb, bias, out);
}

// Round 4
// 112.095 us; speedup vs baseline: 2.1997x; 1.2099x over previous
//
#include <hip/hip_runtime.h>

#define N_NODES 10000
#define N_EDGES 320000
#define KDIM 640            // 5 * 128
#define C_OUT 128

typedef __attribute__((ext_vector_type(8))) short short8;   // 8 bf16
typedef __attribute__((ext_vector_type(4))) float floatx4;  // MFMA C/D

// ---- bf16 helpers ---------------------------------------------------------
__device__ __forceinline__ unsigned short f2bf(float f) {
    unsigned int b = __float_as_uint(f);
    b = (b + 0x7FFFu + ((b >> 16) & 1u)) >> 16;   // RNE
    return (unsigned short)b;
}
__device__ __forceinline__ unsigned int pack2(float x, float y) {
    return (unsigned int)f2bf(x) | ((unsigned int)f2bf(y) << 16);
}
__device__ __forceinline__ float2 unpack2(unsigned int u) {
    float2 r;
    r.x = __uint_as_float(u << 16);
    r.y = __uint_as_float(u & 0xFFFF0000u);
    return r;
}

// ---------------------------------------------------------------------------
// Prep kernel: one launch, three block roles.
//   [0,1250)    : h (f32) -> hb (bf16), uint2-vectorized
//   [1250,1330) : W (640x128 f32) -> Wt (128x640 bf16) transposed
//   [1330,1370) : CSR offsets via binary search over sorted src
// ---------------------------------------------------------------------------
__global__ __launch_bounds__(256) void prep(
        const float* __restrict__ h, uint2* __restrict__ hb4,
        const float* __restrict__ W, unsigned short* __restrict__ Wt,
        const int* __restrict__ src, int* __restrict__ offsets) {
    const int bid = blockIdx.x;
    const int tid = threadIdx.x;

    if (bid < 1250) {                       // conv_h: 1250*256 = 320000 exact
        const int t = bid * 256 + tid;
        float4 v = ((const float4*)h)[t];
        uint2 o;
        o.x = pack2(v.x, v.y);
        o.y = pack2(v.z, v.w);
        hb4[t] = o;
    } else if (bid < 1330) {                // conv_w transpose, 80 blocks
        __shared__ float tile[32][33];
        const int b = bid - 1250;
        const int k0 = (b % 20) * 32, o0 = (b / 20) * 32;
        const int tx = tid & 31, ty = tid >> 5;      // 32 x 8
#pragma unroll
        for (int i = 0; i < 4; ++i)
            tile[ty + 8 * i][tx] = W[(size_t)(k0 + ty + 8 * i) * C_OUT + o0 + tx];
        __syncthreads();
#pragma unroll
        for (int i = 0; i < 4; ++i)
            Wt[(size_t)(o0 + ty + 8 * i) * KDIM + k0 + tx] = f2bf(tile[tx][ty + 8 * i]);
    } else {                                // offsets, 40 blocks
        const int n = (bid - 1330) * 256 + tid;
        if (n > N_NODES) return;
        int lo = 0, hi = N_EDGES;
        while (lo < hi) {
            int mid = (lo + hi) >> 1;
            if (src[mid] < n) lo = mid + 1; else hi = mid;
        }
        offsets[n] = lo;
    }
}

// ---------------------------------------------------------------------------
// Fused scatter + GEMM. Block = 512 threads (8 waves) = 16 nodes.
// Phase 1 (scatter): wave wv handles nodes m0+2wv, m0+2wv+1. Within a wave,
//   two edge-slots: half-wave s (lanes 32s..32s+31) processes edge 2j+s;
//   lane l holds channels 4l..4l+3 (uint2 = 4 bf16 gather, 256B/half-wave,
//   coalesced). dst + X fetched lane-parallel per 64-edge window, values
//   distributed via __shfl. Halves combined via __shfl(lane^32), rows
//   written to LDS Rs (bf16, pitch 648 -> 2-way max bank aliasing = free).
// Phase 2 (GEMM): out(16x128) = Rs(16x640) x Wt(128x640)^T + bias.
//   8 waves x one 16x16 output tile each (c0 = wv*16); A-frag from LDS
//   (ds_read_b128), B-frag direct from global Wt (L2-hot, identical across
//   blocks); 20 MFMA 16x16x32_bf16 per wave. D: row=quad*4+r, col=lane&15.
// ---------------------------------------------------------------------------
__global__ __launch_bounds__(512, 4) void fused_spectconv(
        const uint2* __restrict__ h4,          // (10000, 32) uint2 = bf16 ch
        const float* __restrict__ X,           // (320000, 5)
        const int* __restrict__ dst,
        const int* __restrict__ offsets,
        const unsigned short* __restrict__ Wt, // (128, 640) bf16
        const float* __restrict__ bias,
        float* __restrict__ out) {
    __shared__ unsigned short Rs[16][648];     // 20.25 KB

    const int tid  = threadIdx.x;
    const int wv   = tid >> 6;                 // 0..7
    const int lane = tid & 63;
    const int slot = lane >> 5;                // edge slot 0/1
    const int l    = lane & 31;                // channel-quad index
    const int m0   = blockIdx.x * 16;          // 625 blocks * 16 = 10000 exact

    for (int nn = 0; nn < 2; ++nn) {
        const int node = m0 + wv * 2 + nn;
        float a0x=0,a0y=0,a0z=0,a0w=0, a1x=0,a1y=0,a1z=0,a1w=0,
              a2x=0,a2y=0,a2z=0,a2w=0, a3x=0,a3y=0,a3z=0,a3w=0,
              a4x=0,a4y=0,a4z=0,a4w=0;

        const int e0 = offsets[node];
        const int e1 = offsets[node + 1];

        for (int base = e0; base < e1; base += 64) {
            const int cnt = min(64, e1 - base);
            const int le  = base + ((lane < cnt) ? lane : (cnt - 1));
            const int dv  = dst[le];
            const float* Xp = X + (size_t)le * 5;
            const float xk0 = Xp[0], xk1 = Xp[1], xk2 = Xp[2],
                        xk3 = Xp[3], xk4 = Xp[4];
            const int nsteps = (cnt + 1) >> 1;

#pragma unroll 2
            for (int j = 0; j < nsteps; ++j) {
                const int  ew    = 2 * j + slot;
                const bool valid = (ew < cnt);
                const int  ewc   = valid ? ew : (cnt - 1);
                const int  d     = __shfl(dv, ewc);
                const uint2 u    = h4[(size_t)d * 32 + l];
                float b0 = __shfl(xk0, ewc), b1 = __shfl(xk1, ewc),
                      b2 = __shfl(xk2, ewc), b3 = __shfl(xk3, ewc),
                      b4 = __shfl(xk4, ewc);
                b0 = valid ? b0 : 0.f;  b1 = valid ? b1 : 0.f;
                b2 = valid ? b2 : 0.f;  b3 = valid ? b3 : 0.f;
                b4 = valid ? b4 : 0.f;
                const float2 lo = unpack2(u.x), hi = unpack2(u.y);
                a0x = fmaf(b0, lo.x, a0x); a0y = fmaf(b0, lo.y, a0y);
                a0z = fmaf(b0, hi.x, a0z); a0w = fmaf(b0, hi.y, a0w);
                a1x = fmaf(b1, lo.x, a1x); a1y = fmaf(b1, lo.y, a1y);
                a1z = fmaf(b1, hi.x, a1z); a1w = fmaf(b1, hi.y, a1w);
                a2x = fmaf(b2, lo.x, a2x); a2y = fmaf(b2, lo.y, a2y);
                a2z = fmaf(b2, hi.x, a2z); a2w = fmaf(b2, hi.y, a2w);
                a3x = fmaf(b3, lo.x, a3x); a3y = fmaf(b3, lo.y, a3y);
                a3z = fmaf(b3, hi.x, a3z); a3w = fmaf(b3, hi.y, a3w);
                a4x = fmaf(b4, lo.x, a4x); a4y = fmaf(b4, lo.y, a4y);
                a4z = fmaf(b4, hi.x, a4z); a4w = fmaf(b4, hi.y, a4w);
            }
        }

        // combine the two edge-slot halves (lane ^ 32 holds the partner)
        a0x += __shfl(a0x, lane ^ 32); a0y += __shfl(a0y, lane ^ 32);
        a0z += __shfl(a0z, lane ^ 32); a0w += __shfl(a0w, lane ^ 32);
        a1x += __shfl(a1x, lane ^ 32); a1y += __shfl(a1y, lane ^ 32);
        a1z += __shfl(a1z, lane ^ 32); a1w += __shfl(a1w, lane ^ 32);
        a2x += __shfl(a2x, lane ^ 32); a2y += __shfl(a2y, lane ^ 32);
        a2z += __shfl(a2z, lane ^ 32); a2w += __shfl(a2w, lane ^ 32);
        a3x += __shfl(a3x, lane ^ 32); a3y += __shfl(a3y, lane ^ 32);
        a3z += __shfl(a3z, lane ^ 32); a3w += __shfl(a3w, lane ^ 32);
        a4x += __shfl(a4x, lane ^ 32); a4y += __shfl(a4y, lane ^ 32);
        a4z += __shfl(a4z, lane ^ 32); a4w += __shfl(a4w, lane ^ 32);

        if (lane < 32) {
            const int nrel = wv * 2 + nn;
            uint2 w0; w0.x = pack2(a0x, a0y); w0.y = pack2(a0z, a0w);
            uint2 w1; w1.x = pack2(a1x, a1y); w1.y = pack2(a1z, a1w);
            uint2 w2; w2.x = pack2(a2x, a2y); w2.y = pack2(a2z, a2w);
            uint2 w3; w3.x = pack2(a3x, a3y); w3.y = pack2(a3z, a3w);
            uint2 w4; w4.x = pack2(a4x, a4y); w4.y = pack2(a4z, a4w);
            *(uint2*)&Rs[nrel][0 * 128 + 4 * l] = w0;
            *(uint2*)&Rs[nrel][1 * 128 + 4 * l] = w1;
            *(uint2*)&Rs[nrel][2 * 128 + 4 * l] = w2;
            *(uint2*)&Rs[nrel][3 * 128 + 4 * l] = w3;
            *(uint2*)&Rs[nrel][4 * 128 + 4 * l] = w4;
        }
    }

    __syncthreads();

    // ---- GEMM phase ----
    const int col  = lane & 15;
    const int quad = lane >> 4;
    const int c0   = wv * 16;

    floatx4 acc = {0.f, 0.f, 0.f, 0.f};
    const unsigned short* wrow = Wt + (size_t)(c0 + col) * KDIM + quad * 8;

#pragma unroll
    for (int kc = 0; kc < 20; ++kc) {
        const short8 af = *(const short8*)&Rs[col][kc * 32 + quad * 8];
        const short8 bf = *(const short8*)(wrow + kc * 32);
        acc = __builtin_amdgcn_mfma_f32_16x16x32_bf16(af, bf, acc, 0, 0, 0);
    }

    const float bv = bias[c0 + col];
#pragma unroll
    for (int r = 0; r < 4; ++r) {
        const int m = m0 + quad * 4 + r;
        out[(size_t)m * C_OUT + c0 + col] = acc[r] + bv;
    }
}

// ---------------------------------------------------------------------------
extern "C" void kernel_launch(void* const* d_in, const int* in_sizes, int n_in,
                              void* d_out, int out_size, void* d_ws, size_t ws_size,
                              hipStream_t stream) {
    const float* h      = (const float*)d_in[0];   // (10000,128)
    const float* X      = (const float*)d_in[1];   // (320000,5)
    const int*   ei     = (const int*)d_in[2];     // (2,320000)
    const float* weight = (const float*)d_in[4];   // (5,128,128) == W(640,128)
    const float* bias   = (const float*)d_in[5];   // (128,)
    float* out = (float*)d_out;

    const int* src = ei;
    const int* dst = ei + N_EDGES;

    // Workspace: offsets [0,64KB) | hb bf16 [64KB, +2.56MB) | Wt bf16 [+4MB,..)
    char* wsb = (char*)d_ws;
    int*            offsets = (int*)wsb;
    uint2*          hb4     = (uint2*)(wsb + (64 << 10));
    unsigned short* Wtb     = (unsigned short*)(wsb + (64 << 10) + (4 << 20));

    prep<<<1370, 256, 0, stream>>>(h, hb4, weight, Wtb, src, offsets);
    fused_spectconv<<<625, 512, 0, stream>>>(hb4, X, dst, offsets, Wtb, bias, out);
}

// Round 5
// 107.391 us; speedup vs baseline: 2.2960x; 1.0438x over previous
//
#include <hip/hip_runtime.h>

#define N_NODES 10000
#define N_EDGES 320000
#define KDIM 640            // 5 * 128
#define C_OUT 128

typedef __attribute__((ext_vector_type(8))) short short8;   // 8 bf16
typedef __attribute__((ext_vector_type(4))) float floatx4;  // MFMA C/D

// ---- bf16 helpers ---------------------------------------------------------
__device__ __forceinline__ unsigned short f2bf(float f) {
    unsigned int b = __float_as_uint(f);
    b = (b + 0x7FFFu + ((b >> 16) & 1u)) >> 16;   // RNE
    return (unsigned short)b;
}
__device__ __forceinline__ unsigned int pack2(float x, float y) {
    return (unsigned int)f2bf(x) | ((unsigned int)f2bf(y) << 16);
}
__device__ __forceinline__ float2 unpack2(unsigned int u) {
    float2 r;
    r.x = __uint_as_float(u << 16);
    r.y = __uint_as_float(u & 0xFFFF0000u);
    return r;
}

// ---------------------------------------------------------------------------
// Prep kernel: one launch, three block roles.
//   [0,1250)    : h (f32) -> hb (bf16), uint2-vectorized
//   [1250,1330) : W (640x128 f32) -> Wt (128x640 bf16) transposed
//   [1330,1370) : CSR offsets via binary search over sorted src
// ---------------------------------------------------------------------------
__global__ __launch_bounds__(256) void prep(
        const float* __restrict__ h, uint2* __restrict__ hb4,
        const float* __restrict__ W, unsigned short* __restrict__ Wt,
        const int* __restrict__ src, int* __restrict__ offsets) {
    const int bid = blockIdx.x;
    const int tid = threadIdx.x;

    if (bid < 1250) {                       // conv_h: 1250*256 = 320000 exact
        const int t = bid * 256 + tid;
        float4 v = ((const float4*)h)[t];
        uint2 o;
        o.x = pack2(v.x, v.y);
        o.y = pack2(v.z, v.w);
        hb4[t] = o;
    } else if (bid < 1330) {                // conv_w transpose, 80 blocks
        __shared__ float tile[32][33];
        const int b = bid - 1250;
        const int k0 = (b % 20) * 32, o0 = (b / 20) * 32;
        const int tx = tid & 31, ty = tid >> 5;      // 32 x 8
#pragma unroll
        for (int i = 0; i < 4; ++i)
            tile[ty + 8 * i][tx] = W[(size_t)(k0 + ty + 8 * i) * C_OUT + o0 + tx];
        __syncthreads();
#pragma unroll
        for (int i = 0; i < 4; ++i)
            Wt[(size_t)(o0 + ty + 8 * i) * KDIM + k0 + tx] = f2bf(tile[tx][ty + 8 * i]);
    } else {                                // offsets, 40 blocks
        const int n = (bid - 1330) * 256 + tid;
        if (n > N_NODES) return;
        int lo = 0, hi = N_EDGES;
        while (lo < hi) {
            int mid = (lo + hi) >> 1;
            if (src[mid] < n) lo = mid + 1; else hi = mid;
        }
        offsets[n] = lo;
    }
}

// ---------------------------------------------------------------------------
// Fused scatter + GEMM. Block = 512 threads (8 waves) = 16 nodes.
//
// Phase 1 (scatter): ONE NODE PER HALF-WAVE (node = m0 + wv*2 + slot).
//   Lane l (l = lane&31) holds channels 4l..4l+3. Per edge e of the node:
//   dst[e] and X[e][0..4] are uniform across the half-wave -> plain per-lane
//   loads, coalesced by the TA into single requests (NO ds_bpermute; round-4
//   profiling showed the 6-bperm/step chain was the bottleneck). The only
//   per-lane gather is h4[d*32+l] (256 B/half-wave, coalesced). unroll 4 ->
//   4 independent dst->gather chains in flight. Divergent trip counts between
//   the two half-waves cost max(E0,E1) (~+15% for Poisson(32) degrees).
//   Rows land in LDS Rs as bf16 (pitch 648 -> 2-way max aliasing = free).
//
// Phase 2 (GEMM): out(16x128) = Rs(16x640) x Wt(128x640)^T + bias.
//   One 16x16 output tile per wave (c0 = wv*16); A-frag from LDS
//   (ds_read_b128), B-frag direct from global Wt (L2-hot, shared across
//   blocks); 20 MFMA 16x16x32_bf16 per wave. D: row=quad*4+r, col=lane&15
//   (verified in rounds 3-4, absmax 0.25).
// ---------------------------------------------------------------------------
__global__ __launch_bounds__(512, 4) void fused_spectconv(
        const uint2* __restrict__ h4,          // (10000, 32) uint2 = 4 bf16 ch
        const float* __restrict__ X,           // (320000, 5)
        const int* __restrict__ dst,
        const int* __restrict__ offsets,
        const unsigned short* __restrict__ Wt, // (128, 640) bf16
        const float* __restrict__ bias,
        float* __restrict__ out) {
    __shared__ unsigned short Rs[16][648];     // 20.25 KB

    const int tid  = threadIdx.x;
    const int wv   = tid >> 6;                 // 0..7
    const int lane = tid & 63;
    const int slot = lane >> 5;                // which node of the pair
    const int l    = lane & 31;                // channel-quad index
    const int m0   = blockIdx.x * 16;          // 625 blocks * 16 = 10000 exact

    const int node = m0 + wv * 2 + slot;

    float a0x=0,a0y=0,a0z=0,a0w=0, a1x=0,a1y=0,a1z=0,a1w=0,
          a2x=0,a2y=0,a2z=0,a2w=0, a3x=0,a3y=0,a3z=0,a3w=0,
          a4x=0,a4y=0,a4z=0,a4w=0;

    const int e0 = offsets[node];
    const int e1 = offsets[node + 1];

#pragma unroll 4
    for (int e = e0; e < e1; ++e) {
        const int d = dst[e];                  // uniform in half-wave
        const float x0 = X[(size_t)e * 5 + 0];
        const float x1 = X[(size_t)e * 5 + 1];
        const float x2 = X[(size_t)e * 5 + 2];
        const float x3 = X[(size_t)e * 5 + 3];
        const float x4 = X[(size_t)e * 5 + 4];
        const uint2 u  = h4[(size_t)d * 32 + l];
        const float2 lo = unpack2(u.x), hi = unpack2(u.y);
        a0x = fmaf(x0, lo.x, a0x); a0y = fmaf(x0, lo.y, a0y);
        a0z = fmaf(x0, hi.x, a0z); a0w = fmaf(x0, hi.y, a0w);
        a1x = fmaf(x1, lo.x, a1x); a1y = fmaf(x1, lo.y, a1y);
        a1z = fmaf(x1, hi.x, a1z); a1w = fmaf(x1, hi.y, a1w);
        a2x = fmaf(x2, lo.x, a2x); a2y = fmaf(x2, lo.y, a2y);
        a2z = fmaf(x2, hi.x, a2z); a2w = fmaf(x2, hi.y, a2w);
        a3x = fmaf(x3, lo.x, a3x); a3y = fmaf(x3, lo.y, a3y);
        a3z = fmaf(x3, hi.x, a3z); a3w = fmaf(x3, hi.y, a3w);
        a4x = fmaf(x4, lo.x, a4x); a4y = fmaf(x4, lo.y, a4y);
        a4z = fmaf(x4, hi.x, a4z); a4w = fmaf(x4, hi.y, a4w);
    }

    {
        const int nrel = wv * 2 + slot;
        uint2 w0; w0.x = pack2(a0x, a0y); w0.y = pack2(a0z, a0w);
        uint2 w1; w1.x = pack2(a1x, a1y); w1.y = pack2(a1z, a1w);
        uint2 w2; w2.x = pack2(a2x, a2y); w2.y = pack2(a2z, a2w);
        uint2 w3; w3.x = pack2(a3x, a3y); w3.y = pack2(a3z, a3w);
        uint2 w4; w4.x = pack2(a4x, a4y); w4.y = pack2(a4z, a4w);
        *(uint2*)&Rs[nrel][0 * 128 + 4 * l] = w0;
        *(uint2*)&Rs[nrel][1 * 128 + 4 * l] = w1;
        *(uint2*)&Rs[nrel][2 * 128 + 4 * l] = w2;
        *(uint2*)&Rs[nrel][3 * 128 + 4 * l] = w3;
        *(uint2*)&Rs[nrel][4 * 128 + 4 * l] = w4;
    }

    __syncthreads();

    // ---- GEMM phase ----
    const int col  = lane & 15;
    const int quad = lane >> 4;
    const int c0   = wv * 16;

    floatx4 acc = {0.f, 0.f, 0.f, 0.f};
    const unsigned short* wrow = Wt + (size_t)(c0 + col) * KDIM + quad * 8;

#pragma unroll
    for (int kc = 0; kc < 20; ++kc) {
        const short8 af = *(const short8*)&Rs[col][kc * 32 + quad * 8];
        const short8 bf = *(const short8*)(wrow + kc * 32);
        acc = __builtin_amdgcn_mfma_f32_16x16x32_bf16(af, bf, acc, 0, 0, 0);
    }

    const float bv = bias[c0 + col];
#pragma unroll
    for (int r = 0; r < 4; ++r) {
        const int m = m0 + quad * 4 + r;
        out[(size_t)m * C_OUT + c0 + col] = acc[r] + bv;
    }
}

// ---------------------------------------------------------------------------
extern "C" void kernel_launch(void* const* d_in, const int* in_sizes, int n_in,
                              void* d_out, int out_size, void* d_ws, size_t ws_size,
                              hipStream_t stream) {
    const float* h      = (const float*)d_in[0];   // (10000,128)
    const float* X      = (const float*)d_in[1];   // (320000,5)
    const int*   ei     = (const int*)d_in[2];     // (2,320000)
    const float* weight = (const float*)d_in[4];   // (5,128,128) == W(640,128)
    const float* bias   = (const float*)d_in[5];   // (128,)
    float* out = (float*)d_out;

    const int* src = ei;
    const int* dst = ei + N_EDGES;

    // Workspace: offsets [0,64KB) | hb bf16 [64KB, +2.56MB) | Wt bf16 [+4MB,..)
    char* wsb = (char*)d_ws;
    int*            offsets = (int*)wsb;
    uint2*          hb4     = (uint2*)(wsb + (64 << 10));
    unsigned short* Wtb     = (unsigned short*)(wsb + (64 << 10) + (4 << 20));

    prep<<<1370, 256, 0, stream>>>(h, hb4, weight, Wtb, src, offsets);
    fused_spectconv<<<625, 512, 0, stream>>>(hb4, X, dst, offsets, Wtb, bias, out);
}

// Round 7
// 103.967 us; speedup vs baseline: 2.3716x; 1.0329x over previous
//
#include <hip/hip_runtime.h>

#define N_NODES 10000
#define N_EDGES 320000
#define KDIM 640            // 5 * 128
#define C_OUT 128
#define ECHUNK 768          // max staged edges per block chunk

typedef __attribute__((ext_vector_type(8))) short short8;   // 8 bf16
typedef __attribute__((ext_vector_type(4))) float floatx4;  // MFMA C/D + nt loads
typedef __attribute__((ext_vector_type(2))) unsigned int uintx2;

// ---- bf16 helpers ---------------------------------------------------------
__device__ __forceinline__ unsigned short f2bf(float f) {
    unsigned int b = __float_as_uint(f);
    b = (b + 0x7FFFu + ((b >> 16) & 1u)) >> 16;   // RNE
    return (unsigned short)b;
}
__device__ __forceinline__ unsigned int pack2(float x, float y) {
    return (unsigned int)f2bf(x) | ((unsigned int)f2bf(y) << 16);
}
__device__ __forceinline__ float2 unpack2(unsigned int u) {
    float2 r;
    r.x = __uint_as_float(u << 16);
    r.y = __uint_as_float(u & 0xFFFF0000u);
    return r;
}

// ---------------------------------------------------------------------------
// Prep kernel: one launch, three block roles.
//   [0,1250)    : h (f32) -> hb (bf16)   (nt reads; cached writes)
//   [1250,1330) : W -> Wt (128x640 bf16) transposed
//   [1330,1370) : CSR offsets via binary search over sorted src
// ---------------------------------------------------------------------------
__global__ __launch_bounds__(256) void prep(
        const float* __restrict__ h, uintx2* __restrict__ hb4,
        const float* __restrict__ W, unsigned short* __restrict__ Wt,
        const int* __restrict__ src, int* __restrict__ offsets) {
    const int bid = blockIdx.x;
    const int tid = threadIdx.x;

    if (bid < 1250) {                       // conv_h: 1250*256 = 320000 exact
        const int t = bid * 256 + tid;
        floatx4 v = __builtin_nontemporal_load(&((const floatx4*)h)[t]);
        uintx2 o;
        o.x = pack2(v.x, v.y);
        o.y = pack2(v.z, v.w);
        hb4[t] = o;                         // cached: want hb4 L2-resident
    } else if (bid < 1330) {                // conv_w transpose, 80 blocks
        __shared__ float tile[32][33];
        const int b = bid - 1250;
        const int k0 = (b % 20) * 32, o0 = (b / 20) * 32;
        const int tx = tid & 31, ty = tid >> 5;      // 32 x 8
#pragma unroll
        for (int i = 0; i < 4; ++i)
            tile[ty + 8 * i][tx] =
                __builtin_nontemporal_load(&W[(size_t)(k0 + ty + 8 * i) * C_OUT + o0 + tx]);
        __syncthreads();
#pragma unroll
        for (int i = 0; i < 4; ++i)
            Wt[(size_t)(o0 + ty + 8 * i) * KDIM + k0 + tx] = f2bf(tile[tx][ty + 8 * i]);
    } else {                                // offsets, 40 blocks
        const int n = (bid - 1330) * 256 + tid;
        if (n > N_NODES) return;
        int lo = 0, hi = N_EDGES;
        while (lo < hi) {
            int mid = (lo + hi) >> 1;
            if (src[mid] < n) lo = mid + 1; else hi = mid;
        }
        offsets[n] = lo;
    }
}

// ---------------------------------------------------------------------------
// Fused scatter + GEMM. Block = 512 threads (8 waves) = 16 nodes.
//
// Phase 0 (stage): the block's 16 nodes own a CONTIGUOUS edge range
//   [offsets[m0], offsets[m0+16]) (~512 edges, src-sorted). Bulk-load dst +
//   X rows for the range into LDS with coalesced NONTEMPORAL dword loads
//   (chunked at 768 edges; re-stages if a block exceeds that).
//   -> inner loop has NO vmem traffic for dst/X (round-5 had 6 extra vmem
//   instrs/edge) and the streams don't evict hb4 from L2.
//
// Phase 1 (scatter): one node per half-wave; lane l = channels 4l..4l+3.
//   Per edge: broadcast ds_reads of dst/X + one coalesced uint2 gather of
//   h4 (cached; 2.56 MB working set should now stay L2-resident). unroll 4
//   -> 4 gathers in flight. Accumulate f32, write Rs bf16 (pitch 648).
//
// Phase 2 (GEMM): out(16x128) = Rs(16x640) x Wt(128x640)^T + bias.
//   One 16x16 tile per wave; 20x mfma_f32_16x16x32_bf16; D row=quad*4+r,
//   col=lane&15 (verified rounds 3-5). out stores nontemporal.
// ---------------------------------------------------------------------------
__global__ __launch_bounds__(512, 4) void fused_spectconv(
        const uintx2* __restrict__ h4,         // (10000, 32) uintx2 = 4 bf16 ch
        const float* __restrict__ X,           // (320000, 5)
        const int* __restrict__ dst,
        const int* __restrict__ offsets,
        const unsigned short* __restrict__ Wt, // (128, 640) bf16
        const float* __restrict__ bias,
        float* __restrict__ out) {
    __shared__ unsigned short Rs[16][648];     // 20.25 KB
    __shared__ float Xs[ECHUNK * 5];           // 15.36 KB
    __shared__ int   Ds[ECHUNK];               // 3 KB

    const int tid  = threadIdx.x;
    const int wv   = tid >> 6;                 // 0..7
    const int lane = tid & 63;
    const int slot = lane >> 5;                // which node of the pair
    const int l    = lane & 31;                // channel-quad index
    const int m0   = blockIdx.x * 16;          // 625 blocks * 16 = 10000 exact

    const int node  = m0 + wv * 2 + slot;
    const int e0    = offsets[node];
    const int e1    = offsets[node + 1];
    const int eblk0 = offsets[m0];
    const int eblk1 = offsets[m0 + 16];

    float a0x=0,a0y=0,a0z=0,a0w=0, a1x=0,a1y=0,a1z=0,a1w=0,
          a2x=0,a2y=0,a2z=0,a2w=0, a3x=0,a3y=0,a3z=0,a3w=0,
          a4x=0,a4y=0,a4z=0,a4w=0;

    for (int chunk = eblk0; chunk < eblk1; chunk += ECHUNK) {
        const int cn = min(ECHUNK, eblk1 - chunk);

        if (chunk != eblk0) __syncthreads();   // protect LDS reuse on re-stage
        for (int i = tid; i < cn; i += 512)
            Ds[i] = __builtin_nontemporal_load(&dst[chunk + i]);
        for (int i = tid; i < cn * 5; i += 512)
            Xs[i] = __builtin_nontemporal_load(&X[(size_t)chunk * 5 + i]);
        __syncthreads();

        const int es = max(e0, chunk);
        const int ee = min(e1, chunk + cn);

#pragma unroll 4
        for (int e = es; e < ee; ++e) {
            const int idx = e - chunk;
            const int d   = Ds[idx];                     // broadcast ds_read
            const float x0 = Xs[idx * 5 + 0];
            const float x1 = Xs[idx * 5 + 1];
            const float x2 = Xs[idx * 5 + 2];
            const float x3 = Xs[idx * 5 + 3];
            const float x4 = Xs[idx * 5 + 4];
            const uintx2 u = h4[(size_t)d * 32 + l];     // cached gather
            const float2 lo = unpack2(u.x), hi = unpack2(u.y);
            a0x = fmaf(x0, lo.x, a0x); a0y = fmaf(x0, lo.y, a0y);
            a0z = fmaf(x0, hi.x, a0z); a0w = fmaf(x0, hi.y, a0w);
            a1x = fmaf(x1, lo.x, a1x); a1y = fmaf(x1, lo.y, a1y);
            a1z = fmaf(x1, hi.x, a1z); a1w = fmaf(x1, hi.y, a1w);
            a2x = fmaf(x2, lo.x, a2x); a2y = fmaf(x2, lo.y, a2y);
            a2z = fmaf(x2, hi.x, a2z); a2w = fmaf(x2, hi.y, a2w);
            a3x = fmaf(x3, lo.x, a3x); a3y = fmaf(x3, lo.y, a3y);
            a3z = fmaf(x3, hi.x, a3z); a3w = fmaf(x3, hi.y, a3w);
            a4x = fmaf(x4, lo.x, a4x); a4y = fmaf(x4, lo.y, a4y);
            a4z = fmaf(x4, hi.x, a4z); a4w = fmaf(x4, hi.y, a4w);
        }
    }

    {
        const int nrel = wv * 2 + slot;
        uintx2 w0; w0.x = pack2(a0x, a0y); w0.y = pack2(a0z, a0w);
        uintx2 w1; w1.x = pack2(a1x, a1y); w1.y = pack2(a1z, a1w);
        uintx2 w2; w2.x = pack2(a2x, a2y); w2.y = pack2(a2z, a2w);
        uintx2 w3; w3.x = pack2(a3x, a3y); w3.y = pack2(a3z, a3w);
        uintx2 w4; w4.x = pack2(a4x, a4y); w4.y = pack2(a4z, a4w);
        *(uintx2*)&Rs[nrel][0 * 128 + 4 * l] = w0;
        *(uintx2*)&Rs[nrel][1 * 128 + 4 * l] = w1;
        *(uintx2*)&Rs[nrel][2 * 128 + 4 * l] = w2;
        *(uintx2*)&Rs[nrel][3 * 128 + 4 * l] = w3;
        *(uintx2*)&Rs[nrel][4 * 128 + 4 * l] = w4;
    }

    __syncthreads();

    // ---- GEMM phase ----
    const int col  = lane & 15;
    const int quad = lane >> 4;
    const int c0   = wv * 16;

    floatx4 acc = {0.f, 0.f, 0.f, 0.f};
    const unsigned short* wrow = Wt + (size_t)(c0 + col) * KDIM + quad * 8;

#pragma unroll
    for (int kc = 0; kc < 20; ++kc) {
        const short8 af = *(const short8*)&Rs[col][kc * 32 + quad * 8];
        const short8 bf = *(const short8*)(wrow + kc * 32);
        acc = __builtin_amdgcn_mfma_f32_16x16x32_bf16(af, bf, acc, 0, 0, 0);
    }

    const float bv = bias[c0 + col];
#pragma unroll
    for (int r = 0; r < 4; ++r) {
        const int m = m0 + quad * 4 + r;
        __builtin_nontemporal_store(acc[r] + bv, &out[(size_t)m * C_OUT + c0 + col]);
    }
}

// ---------------------------------------------------------------------------
extern "C" void kernel_launch(void* const* d_in, const int* in_sizes, int n_in,
                              void* d_out, int out_size, void* d_ws, size_t ws_size,
                              hipStream_t stream) {
    const float* h      = (const float*)d_in[0];   // (10000,128)
    const float* X      = (const float*)d_in[1];   // (320000,5)
    const int*   ei     = (const int*)d_in[2];     // (2,320000)
    const float* weight = (const float*)d_in[4];   // (5,128,128) == W(640,128)
    const float* bias   = (const float*)d_in[5];   // (128,)
    float* out = (float*)d_out;

    const int* src = ei;
    const int* dst = ei + N_EDGES;

    // Workspace: offsets [0,64KB) | hb bf16 [64KB, +2.56MB) | Wt bf16 [+4MB,..)
    char* wsb = (char*)d_ws;
    int*            offsets = (int*)wsb;
    uintx2*         hb4     = (uintx2*)(wsb + (64 << 10));
    unsigned short* Wtb     = (unsigned short*)(wsb + (64 << 10) + (4 << 20));

    prep<<<1370, 256, 0, stream>>>(h, hb4, weight, Wtb, src, offsets);
    fused_spectconv<<<625, 512, 0, stream>>>(hb4, X, dst, offsets, Wtb, bias, out);
}